// Round 1
// baseline (230.719 us; speedup 1.0000x reference)
//
#include <hip/hip_runtime.h>
#include <hip/hip_cooperative_groups.h>

namespace cg = cooperative_groups;

// out = 2 * sum((img1-img2)^2) / N,  N = B*C*H*W  (H==W collapses the
// row-mean + col-mean structure to a single full-tensor mean).
//
// Single cooperative dispatch: grid-stride BW-bound squared-diff reduce,
// per-block partial to workspace, grid.sync(), block 0 folds partials.
// Deterministic (fixed reduction tree, no float atomics — 1024
// same-address fp32 atomics cost ~8 µs, measured in a prior round).

#define BLOCK 256
#define GRID  1024   // 4 blocks/CU co-resident (needed for grid.sync)

__device__ __forceinline__ float block_reduce(float acc, float* wsum) {
    // wave64 butterfly
    #pragma unroll
    for (int off = 32; off > 0; off >>= 1)
        acc += __shfl_down(acc, off, 64);
    const int lane = threadIdx.x & 63;
    const int wave = threadIdx.x >> 6;
    if (lane == 0) wsum[wave] = acc;
    __syncthreads();
    float s = 0.f;
    if (threadIdx.x == 0) {
        #pragma unroll
        for (int k = 0; k < BLOCK / 64; ++k) s += wsum[k];
    }
    return s;  // valid on thread 0 only
}

__global__ __launch_bounds__(BLOCK, 4) void fused_sq_sum(
    const float4* __restrict__ a4, const float4* __restrict__ b4,
    long n4,
    const float* __restrict__ a, const float* __restrict__ b,
    long tail_start, long n,
    float* __restrict__ partials, float* __restrict__ out, float scale)
{
    const long T   = (long)gridDim.x * BLOCK;
    const long tid = (long)blockIdx.x * BLOCK + threadIdx.x;

    float acc0 = 0.f, acc1 = 0.f, acc2 = 0.f, acc3 = 0.f;

    long i = tid;
    // 4-way unroll: 8 independent 16B loads in flight per thread.
    // For n = 16*3*512*512: n4/T = 12 -> exactly 3 iterations, no remainder.
    for (; i + 3 * T < n4; i += 4 * T) {
        float4 av0 = a4[i];         float4 bv0 = b4[i];
        float4 av1 = a4[i + T];     float4 bv1 = b4[i + T];
        float4 av2 = a4[i + 2*T];   float4 bv2 = b4[i + 2*T];
        float4 av3 = a4[i + 3*T];   float4 bv3 = b4[i + 3*T];
        float d;
        d = av0.x-bv0.x; acc0 += d*d;  d = av0.y-bv0.y; acc0 += d*d;
        d = av0.z-bv0.z; acc0 += d*d;  d = av0.w-bv0.w; acc0 += d*d;
        d = av1.x-bv1.x; acc1 += d*d;  d = av1.y-bv1.y; acc1 += d*d;
        d = av1.z-bv1.z; acc1 += d*d;  d = av1.w-bv1.w; acc1 += d*d;
        d = av2.x-bv2.x; acc2 += d*d;  d = av2.y-bv2.y; acc2 += d*d;
        d = av2.z-bv2.z; acc2 += d*d;  d = av2.w-bv2.w; acc2 += d*d;
        d = av3.x-bv3.x; acc3 += d*d;  d = av3.y-bv3.y; acc3 += d*d;
        d = av3.z-bv3.z; acc3 += d*d;  d = av3.w-bv3.w; acc3 += d*d;
    }
    for (; i < n4; i += T) {
        float4 av = a4[i]; float4 bv = b4[i];
        float d;
        d = av.x-bv.x; acc0 += d*d;  d = av.y-bv.y; acc0 += d*d;
        d = av.z-bv.z; acc0 += d*d;  d = av.w-bv.w; acc0 += d*d;
    }
    // scalar tail if n % 4 != 0 (not hit for 16*3*512*512, but safe)
    for (long j = tail_start + tid; j < n; j += T) {
        float d = a[j] - b[j];
        acc0 += d * d;
    }
    float acc = (acc0 + acc1) + (acc2 + acc3);

    __shared__ float wsum[BLOCK / 64];
    float s = block_reduce(acc, wsum);
    if (threadIdx.x == 0) partials[blockIdx.x] = s;

    // grid-wide barrier (includes device-scope memory ordering)
    cg::this_grid().sync();

    if (blockIdx.x == 0) {
        float v = 0.f;
        for (int k = threadIdx.x; k < GRID; k += BLOCK) v += partials[k];
        // wsum reuse is safe: grid.sync() included a block barrier
        float total = block_reduce(v, wsum);
        if (threadIdx.x == 0) out[0] = total * scale;
    }
}

extern "C" void kernel_launch(void* const* d_in, const int* in_sizes, int n_in,
                              void* d_out, int out_size, void* d_ws, size_t ws_size,
                              hipStream_t stream) {
    const float*  a  = (const float*)d_in[0];
    const float*  b  = (const float*)d_in[1];
    float*        out = (float*)d_out;
    long n  = (long)in_sizes[0];
    long n4 = n / 4;
    long tail_start = n4 * 4;

    const float4* a4 = (const float4*)a;
    const float4* b4 = (const float4*)b;
    float* partials  = (float*)d_ws;   // GRID floats, deterministically overwritten
    float  scale     = 2.0f / (float)n;

    void* args[] = {
        (void*)&a4, (void*)&b4, (void*)&n4,
        (void*)&a, (void*)&b, (void*)&tail_start, (void*)&n,
        (void*)&partials, (void*)&out, (void*)&scale
    };
    hipLaunchCooperativeKernel((void*)fused_sq_sum, dim3(GRID), dim3(BLOCK),
                               args, 0, stream);
}

// Round 2
// 164.951 us; speedup vs baseline: 1.3987x; 1.3987x over previous
//
#include <hip/hip_runtime.h>

// out = 2 * sum((img1-img2)^2) / N,  N = B*C*H*W  (H==W collapses the
// row-mean + col-mean structure to a single full-tensor mean).
//
// Single compute dispatch. Each block writes a partial sum; the LAST block
// to finish (detected via counter atomicAdd — threadfence reduction
// pattern) folds the 1024 partials in a fixed order. Bitwise deterministic:
// the fold order is independent of which block performs it. No float
// atomics, no cooperative grid.sync (measured R1: grid.sync on 8 XCDs
// costs ~110 us of idle spin — catastrophic).
//
// Counter is zeroed by a 4-byte hipMemsetAsync (workspace is re-poisoned
// between iterations, so it cannot be assumed zero).

#define BLOCK 256
#define GRID  1024   // 4 blocks/CU; n4/(GRID*BLOCK) = 12 -> exactly 3 unrolled iters

__device__ __forceinline__ float block_reduce(float acc, float* wsum) {
    #pragma unroll
    for (int off = 32; off > 0; off >>= 1)
        acc += __shfl_down(acc, off, 64);
    const int lane = threadIdx.x & 63;
    const int wave = threadIdx.x >> 6;
    if (lane == 0) wsum[wave] = acc;
    __syncthreads();
    float s = 0.f;
    if (threadIdx.x == 0) {
        #pragma unroll
        for (int k = 0; k < BLOCK / 64; ++k) s += wsum[k];
    }
    return s;  // valid on thread 0 only
}

__global__ __launch_bounds__(BLOCK) void sq_sum_lastblock(
    const float4* __restrict__ a4, const float4* __restrict__ b4,
    long n4,
    const float* __restrict__ a, const float* __restrict__ b,
    long tail_start, long n,
    float* __restrict__ partials, unsigned int* __restrict__ counter,
    float* __restrict__ out, float scale)
{
    const long T   = (long)gridDim.x * BLOCK;
    const long tid = (long)blockIdx.x * BLOCK + threadIdx.x;

    float acc0 = 0.f, acc1 = 0.f, acc2 = 0.f, acc3 = 0.f;

    long i = tid;
    // 4-way unroll: 8 independent 16B loads in flight per thread.
    for (; i + 3 * T < n4; i += 4 * T) {
        float4 av0 = a4[i];         float4 bv0 = b4[i];
        float4 av1 = a4[i + T];     float4 bv1 = b4[i + T];
        float4 av2 = a4[i + 2*T];   float4 bv2 = b4[i + 2*T];
        float4 av3 = a4[i + 3*T];   float4 bv3 = b4[i + 3*T];
        float d;
        d = av0.x-bv0.x; acc0 += d*d;  d = av0.y-bv0.y; acc0 += d*d;
        d = av0.z-bv0.z; acc0 += d*d;  d = av0.w-bv0.w; acc0 += d*d;
        d = av1.x-bv1.x; acc1 += d*d;  d = av1.y-bv1.y; acc1 += d*d;
        d = av1.z-bv1.z; acc1 += d*d;  d = av1.w-bv1.w; acc1 += d*d;
        d = av2.x-bv2.x; acc2 += d*d;  d = av2.y-bv2.y; acc2 += d*d;
        d = av2.z-bv2.z; acc2 += d*d;  d = av2.w-bv2.w; acc2 += d*d;
        d = av3.x-bv3.x; acc3 += d*d;  d = av3.y-bv3.y; acc3 += d*d;
        d = av3.z-bv3.z; acc3 += d*d;  d = av3.w-bv3.w; acc3 += d*d;
    }
    for (; i < n4; i += T) {
        float4 av = a4[i]; float4 bv = b4[i];
        float d;
        d = av.x-bv.x; acc0 += d*d;  d = av.y-bv.y; acc0 += d*d;
        d = av.z-bv.z; acc0 += d*d;  d = av.w-bv.w; acc0 += d*d;
    }
    // scalar tail if n % 4 != 0 (not hit for 16*3*512*512, but safe)
    for (long j = tail_start + tid; j < n; j += T) {
        float d = a[j] - b[j];
        acc0 += d * d;
    }
    float acc = (acc0 + acc1) + (acc2 + acc3);

    __shared__ float wsum[BLOCK / 64];
    float s = block_reduce(acc, wsum);

    __shared__ bool amLast;
    if (threadIdx.x == 0) {
        partials[blockIdx.x] = s;
        __threadfence();                       // release: partial visible device-wide
        unsigned int prev = atomicAdd(counter, 1u);
        amLast = (prev == gridDim.x - 1);
    }
    __syncthreads();

    if (amLast) {
        __threadfence();                       // acquire: see all partials
        volatile const float* vp = partials;   // force device-coherent loads
        float v = 0.f;
        for (int k = threadIdx.x; k < GRID; k += BLOCK) v += vp[k];
        // wsum reuse safe: __syncthreads() above separates the two uses
        float total = block_reduce(v, wsum);
        if (threadIdx.x == 0) out[0] = total * scale;
    }
}

extern "C" void kernel_launch(void* const* d_in, const int* in_sizes, int n_in,
                              void* d_out, int out_size, void* d_ws, size_t ws_size,
                              hipStream_t stream) {
    const float* a = (const float*)d_in[0];
    const float* b = (const float*)d_in[1];
    float* out = (float*)d_out;
    long n  = (long)in_sizes[0];
    long n4 = n / 4;
    long tail_start = n4 * 4;

    float*        partials = (float*)d_ws;                    // GRID floats
    unsigned int* counter  = (unsigned int*)((char*)d_ws + 4096);

    // zero the completion counter (workspace is re-poisoned each iteration)
    hipMemsetAsync(counter, 0, sizeof(unsigned int), stream);

    sq_sum_lastblock<<<GRID, BLOCK, 0, stream>>>(
        (const float4*)a, (const float4*)b, n4,
        a, b, tail_start, n,
        partials, counter, out, 2.0f / (float)n);
}

// Round 3
// 116.213 us; speedup vs baseline: 1.9853x; 1.4194x over previous
//
#include <hip/hip_runtime.h>

// out = 2 * sum((img1-img2)^2) / N,  N = B*C*H*W  (H==W collapses the
// row-mean + col-mean structure to a single full-tensor mean).
//
// Single compute dispatch + 8-byte memset.
//
// Tail protocol (R2 post-mortem: per-block __threadfence = buffer_wbl2+inv
// L2 cache-maintenance ops cost ~55 us of dead tail across 8 XCDs):
// each block's thread-0 does ONE u64 atomicAdd of
//     (fixed_point_partial << 11) | 1.
// Integer adds are associative/commutative -> bitwise deterministic
// regardless of block arrival order. Same-address atomics serialize at the
// device coherence point, so the add that sees count == GRID-1 in its
// RETURN value has, by definition, observed every other block's
// contribution: prev + own = final total. No fences, no partials array,
// no second pass, no volatile reads.
//
// Fixed point: scale 2^23. Per-block partial ~2.5e4, total ~2.5e7
// -> total*2^23 ~ 2^47.6, shifted <<11 -> 2^58.6, safely < 2^63.
// Quantization 2^-23/block * 1024 blocks ~ 5e-12 relative: noise.

#define BLOCK 256
#define GRID  1024   // 4 blocks/CU; n4/(GRID*BLOCK) = 12 for the harness shape
#define CNT_BITS 11  // count field; GRID < 2048 so no wrap into the sum field
#define FP_SCALE 8388608.0  // 2^23

#define ACC4(A,B,S) do { float d_;                  \
    d_ = A.x - B.x; S += d_ * d_;                   \
    d_ = A.y - B.y; S += d_ * d_;                   \
    d_ = A.z - B.z; S += d_ * d_;                   \
    d_ = A.w - B.w; S += d_ * d_; } while (0)

__global__ __launch_bounds__(BLOCK) void sq_sum_onepass(
    const float4* __restrict__ a4, const float4* __restrict__ b4,
    long n4,
    const float* __restrict__ a, const float* __restrict__ b,
    long tail_start, long n,
    unsigned long long* __restrict__ packed,
    float* __restrict__ out, double scale)
{
    const long T   = (long)gridDim.x * BLOCK;
    const long tid = (long)blockIdx.x * BLOCK + threadIdx.x;

    float acc0 = 0.f, acc1 = 0.f, acc2 = 0.f, acc3 = 0.f;
    long i = tid;

    if (n4 == 12 * T) {
        // Exact-shape fast path: 12 strided float4-pairs per thread,
        // software-pipelined in three 4-pair stages so 8-16 loads stay in
        // flight (R2's rolled loop: VGPR=28 -> compiler kept only ~4).
        float4 a0 = a4[i],       b0 = b4[i];
        float4 a1 = a4[i +   T], b1 = b4[i +   T];
        float4 a2 = a4[i + 2*T], b2 = b4[i + 2*T];
        float4 a3 = a4[i + 3*T], b3 = b4[i + 3*T];
        float4 c0 = a4[i + 4*T], d0 = b4[i + 4*T];
        float4 c1 = a4[i + 5*T], d1 = b4[i + 5*T];
        float4 c2 = a4[i + 6*T], d2 = b4[i + 6*T];
        float4 c3 = a4[i + 7*T], d3 = b4[i + 7*T];

        // consume stage A while stage B is outstanding
        ACC4(a0, b0, acc0); ACC4(a1, b1, acc1);
        ACC4(a2, b2, acc2); ACC4(a3, b3, acc3);

        // issue stage A' (reuses stage-A registers) while B is consumed
        a0 = a4[i +  8*T]; b0 = b4[i +  8*T];
        a1 = a4[i +  9*T]; b1 = b4[i +  9*T];
        a2 = a4[i + 10*T]; b2 = b4[i + 10*T];
        a3 = a4[i + 11*T]; b3 = b4[i + 11*T];

        // consume stage B
        ACC4(c0, d0, acc0); ACC4(c1, d1, acc1);
        ACC4(c2, d2, acc2); ACC4(c3, d3, acc3);

        // consume stage A'
        ACC4(a0, b0, acc0); ACC4(a1, b1, acc1);
        ACC4(a2, b2, acc2); ACC4(a3, b3, acc3);

        i += 12 * T;  // == n4 + tid: strided part done
    } else {
        // generic fallback
        for (; i + T < n4; i += 2 * T) {
            float4 av0 = a4[i];     float4 bv0 = b4[i];
            float4 av1 = a4[i + T]; float4 bv1 = b4[i + T];
            ACC4(av0, bv0, acc0);
            ACC4(av1, bv1, acc1);
        }
        for (; i < n4; i += T) {
            float4 av = a4[i]; float4 bv = b4[i];
            ACC4(av, bv, acc0);
        }
    }

    // scalar tail if n % 4 != 0 (not hit for 16*3*512*512, but safe)
    for (long j = tail_start + tid; j < n; j += T) {
        float d = a[j] - b[j];
        acc0 += d * d;
    }

    float acc = (acc0 + acc1) + (acc2 + acc3);

    // wave64 butterfly + cross-wave LDS reduce
    #pragma unroll
    for (int off = 32; off > 0; off >>= 1)
        acc += __shfl_down(acc, off, 64);

    __shared__ float wsum[BLOCK / 64];
    const int lane = threadIdx.x & 63;
    const int wave = threadIdx.x >> 6;
    if (lane == 0) wsum[wave] = acc;
    __syncthreads();

    if (threadIdx.x == 0) {
        float s = 0.f;
        #pragma unroll
        for (int k = 0; k < BLOCK / 64; ++k) s += wsum[k];

        unsigned long long fx = (unsigned long long)((double)s * FP_SCALE);
        unsigned long long pk = (fx << CNT_BITS) | 1ull;
        unsigned long long prev = atomicAdd(packed, pk);
        if ((prev & ((1ull << CNT_BITS) - 1ull)) ==
            (unsigned long long)(gridDim.x - 1)) {
            // we are the last arrival: prev already contains every other
            // block's contribution
            unsigned long long tot = (prev + pk) >> CNT_BITS;
            out[0] = (float)((double)tot * scale);
        }
    }
}

extern "C" void kernel_launch(void* const* d_in, const int* in_sizes, int n_in,
                              void* d_out, int out_size, void* d_ws, size_t ws_size,
                              hipStream_t stream) {
    const float* a = (const float*)d_in[0];
    const float* b = (const float*)d_in[1];
    float* out = (float*)d_out;
    long n  = (long)in_sizes[0];
    long n4 = n / 4;
    long tail_start = n4 * 4;

    unsigned long long* packed = (unsigned long long*)d_ws;

    // workspace is re-poisoned between iterations: zero the accumulator
    hipMemsetAsync(packed, 0, sizeof(unsigned long long), stream);

    // scale = 2/N divided by the fixed-point factor
    double scale = 2.0 / (double)n / FP_SCALE;

    sq_sum_onepass<<<GRID, BLOCK, 0, stream>>>(
        (const float4*)a, (const float4*)b, n4,
        a, b, tail_start, n,
        packed, out, scale);
}

// Round 4
// 113.567 us; speedup vs baseline: 2.0316x; 1.0233x over previous
//
#include <hip/hip_runtime.h>

// out = 2 * sum((img1-img2)^2) / N,  N = B*C*H*W  (H==W collapses the
// row-mean + col-mean structure to a single full-tensor mean).
//
// Two-dispatch deterministic structure (measured best: R0 114.3 us, prior
// session 112.3 us). Measured dead ends this session:
//  - cooperative grid.sync: +110 us idle spin across 8 XCDs (R1)
//  - per-block __threadfence (buffer_wbl2+inv per block): +55 us tail (R2)
//  - memset + packed u64 atomic single-pass: == two-dispatch, not better (R3)
//
// This round: keep the R0 structure, upgrade the main loop to the
// software-pipelined 12-pair fast path (16 loads in flight per thread;
// R0's rolled loop had VGPR=28 -> only ~4 outstanding).

#define BLOCK 256
#define GRID  1024   // 4 blocks/CU; n4/(GRID*BLOCK) = 12 for 16*3*512*512

#define ACC4(A,B,S) do { float d_;                  \
    d_ = A.x - B.x; S += d_ * d_;                   \
    d_ = A.y - B.y; S += d_ * d_;                   \
    d_ = A.z - B.z; S += d_ * d_;                   \
    d_ = A.w - B.w; S += d_ * d_; } while (0)

__global__ __launch_bounds__(BLOCK) void partial_sq_sum(
    const float4* __restrict__ a4, const float4* __restrict__ b4,
    long n4, float* __restrict__ partials)
{
    const long T   = (long)gridDim.x * BLOCK;
    const long tid = (long)blockIdx.x * BLOCK + threadIdx.x;

    float acc0 = 0.f, acc1 = 0.f, acc2 = 0.f, acc3 = 0.f;
    long i = tid;

    if (n4 == 12 * T) {
        // Exact-shape fast path: 12 strided float4-pairs per thread,
        // software-pipelined in three 4-pair stages, 16 loads in flight.
        float4 a0 = a4[i],       b0 = b4[i];
        float4 a1 = a4[i +   T], b1 = b4[i +   T];
        float4 a2 = a4[i + 2*T], b2 = b4[i + 2*T];
        float4 a3 = a4[i + 3*T], b3 = b4[i + 3*T];
        float4 c0 = a4[i + 4*T], d0 = b4[i + 4*T];
        float4 c1 = a4[i + 5*T], d1 = b4[i + 5*T];
        float4 c2 = a4[i + 6*T], d2 = b4[i + 6*T];
        float4 c3 = a4[i + 7*T], d3 = b4[i + 7*T];

        // consume stage A while stage B is outstanding
        ACC4(a0, b0, acc0); ACC4(a1, b1, acc1);
        ACC4(a2, b2, acc2); ACC4(a3, b3, acc3);

        // issue stage A' (reuses stage-A registers) while B is consumed
        a0 = a4[i +  8*T]; b0 = b4[i +  8*T];
        a1 = a4[i +  9*T]; b1 = b4[i +  9*T];
        a2 = a4[i + 10*T]; b2 = b4[i + 10*T];
        a3 = a4[i + 11*T]; b3 = b4[i + 11*T];

        // consume stage B
        ACC4(c0, d0, acc0); ACC4(c1, d1, acc1);
        ACC4(c2, d2, acc2); ACC4(c3, d3, acc3);

        // consume stage A'
        ACC4(a0, b0, acc0); ACC4(a1, b1, acc1);
        ACC4(a2, b2, acc2); ACC4(a3, b3, acc3);
    } else {
        // generic fallback (any shape)
        for (; i + T < n4; i += 2 * T) {
            float4 av0 = a4[i];     float4 bv0 = b4[i];
            float4 av1 = a4[i + T]; float4 bv1 = b4[i + T];
            ACC4(av0, bv0, acc0);
            ACC4(av1, bv1, acc1);
        }
        for (; i < n4; i += T) {
            float4 av = a4[i]; float4 bv = b4[i];
            ACC4(av, bv, acc0);
        }
    }

    float acc = (acc0 + acc1) + (acc2 + acc3);

    // wave64 butterfly
    #pragma unroll
    for (int off = 32; off > 0; off >>= 1)
        acc += __shfl_down(acc, off, 64);

    __shared__ float wsum[BLOCK / 64];
    const int lane = threadIdx.x & 63;
    const int wave = threadIdx.x >> 6;
    if (lane == 0) wsum[wave] = acc;
    __syncthreads();

    if (threadIdx.x == 0) {
        float s = 0.f;
        #pragma unroll
        for (int k = 0; k < BLOCK / 64; ++k) s += wsum[k];
        partials[blockIdx.x] = s;
    }
}

__global__ __launch_bounds__(BLOCK) void final_reduce(
    const float* __restrict__ partials, int nparts,
    const float* __restrict__ a, const float* __restrict__ b,
    long tail_start, long n, float* __restrict__ out, float scale)
{
    float acc = 0.f;
    for (int i = threadIdx.x; i < nparts; i += BLOCK)
        acc += partials[i];

    // scalar tail if n % 4 != 0 (not hit for 16*3*512*512, but safe)
    for (long i = tail_start + threadIdx.x; i < n; i += BLOCK) {
        float d = a[i] - b[i];
        acc += d * d;
    }

    #pragma unroll
    for (int off = 32; off > 0; off >>= 1)
        acc += __shfl_down(acc, off, 64);

    __shared__ float wsum[BLOCK / 64];
    const int lane = threadIdx.x & 63;
    const int wave = threadIdx.x >> 6;
    if (lane == 0) wsum[wave] = acc;
    __syncthreads();

    if (threadIdx.x == 0) {
        float s = 0.f;
        #pragma unroll
        for (int k = 0; k < BLOCK / 64; ++k) s += wsum[k];
        out[0] = s * scale;
    }
}

extern "C" void kernel_launch(void* const* d_in, const int* in_sizes, int n_in,
                              void* d_out, int out_size, void* d_ws, size_t ws_size,
                              hipStream_t stream) {
    const float* a = (const float*)d_in[0];
    const float* b = (const float*)d_in[1];
    float* out = (float*)d_out;
    long n  = (long)in_sizes[0];
    long n4 = n / 4;

    float* partials = (float*)d_ws;  // GRID floats, deterministically overwritten

    partial_sq_sum<<<GRID, BLOCK, 0, stream>>>(
        (const float4*)a, (const float4*)b, n4, partials);

    final_reduce<<<1, BLOCK, 0, stream>>>(
        partials, GRID, a, b, n4 * 4, n, out, 2.0f / (float)n);
}